// Round 5
// baseline (101.238 us; speedup 1.0000x reference)
//
#include <hip/hip_runtime.h>
#include <hip/hip_bf16.h>

// Problem constants (from reference): B=32, L=128, D=48, R=64
#define PB 32
#define PL 128
#define PD 48
#define PR 64

// Register-tiled 2x2 (2 b's x 2 r's per block), grid = 512 blocks,
// 384 threads (6 waves). tid -> lg = tid/12 (L-group 0..31), dq = tid%12.
// vs round 4: same traffic (6 floats/h-element) but 2x the waves/CU
// (6 -> 12, i.e. 1.5 -> 3 waves/SIMD) and half the per-thread L-chain —
// round-4 post-mortem showed the kernel is L2-latency-bound at 19%
// occupancy, not traffic-bound.
__device__ __forceinline__ void compute4(
    const float4 x4, const float4 t4, const float4 m4, const float4 dt4,
    const float4 p4, const float* __restrict__ w20, const float4 bt4,
    const float4 wv4, const float ar, const float refr, float4& acc)
{
    const float xs[4]  = {x4.x,  x4.y,  x4.z,  x4.w};
    const float ts[4]  = {t4.x,  t4.y,  t4.z,  t4.w};
    const float ms[4]  = {m4.x,  m4.y,  m4.z,  m4.w};
    const float dts[4] = {dt4.x, dt4.y, dt4.z, dt4.w};
    const float ps[4]  = {p4.x,  p4.y,  p4.z,  p4.w};
    const float bts[4] = {bt4.x, bt4.y, bt4.z, bt4.w};
    const float wvs[4] = {wv4.x, wv4.y, wv4.z, wv4.w};
    float a[4] = {acc.x, acc.y, acc.z, acc.w};
    #pragma unroll
    for (int j = 0; j < 4; ++j) {
        const float x = xs[j];
        const float dist = fabsf(ts[j] - refr);
        const float kern = __expf(-ar * dist);
        float inten = x * kern;
        inten = inten > 0.0f ? inten : 0.0f;
        float h = w20[j*5 + 0] * x
                + w20[j*5 + 1] * inten
                + w20[j*5 + 2] * ms[j]
                + w20[j*5 + 3] * dts[j]
                + w20[j*5 + 4] * ps[j]
                + 5.0f * bts[j];              // b_t broadcast over 5-axis
        h = h > 0.0f ? h : 0.0f;
        a[j] += wvs[j] * h;
    }
    acc = make_float4(a[0], a[1], a[2], a[3]);
}

__global__ __launch_bounds__(384, 3) void alnn_kernel(
    const float* __restrict__ X,
    const float* __restrict__ T,
    const float* __restrict__ M,
    const float* __restrict__ DT,
    const float* __restrict__ P,
    const float* __restrict__ alpha,
    const float* __restrict__ w_t,
    const float* __restrict__ b_t,
    const float* __restrict__ w_v,
    const float* __restrict__ b_v,
    float* __restrict__ out)
{
    const int bid = blockIdx.x;
    const int rrb = bid & 31;       // r-tile index 0..31
    const int bbb = bid >> 5;       // b-tile index 0..15
    const int r0 = rrb * 2;
    const int b0 = bbb * 2;
    const int tid = threadIdx.x;
    const int lg = tid / 12;        // 0..31
    const int dq = tid - lg * 12;   // 0..11

    __shared__ float4 part[32][49];   // +1 float4 pad
    __shared__ float4 part2[4][49];

    const float ar0 = fmaxf(alpha[r0], 0.0f);
    const float ar1 = fmaxf(alpha[r0 + 1], 0.0f);
    const float refr0 = 48.0f * (float)r0 / 63.0f;        // linspace(0,48,64)
    const float refr1 = 48.0f * (float)(r0 + 1) / 63.0f;

    int io = b0 * (PL * PD) + lg * PD + dq * 4;            // X/T/M/DT/P, b0
    int wo = r0 * (PL * PD * 5) + lg * (PD * 5) + dq * 20; // w_t, r0
    int vo = r0 * (PL * PD) + lg * PD + dq * 4;            // b_t/w_v, r0

    float4 acc00 = make_float4(0.f, 0.f, 0.f, 0.f);  // (b0, r0)
    float4 acc01 = make_float4(0.f, 0.f, 0.f, 0.f);  // (b0, r1)
    float4 acc10 = make_float4(0.f, 0.f, 0.f, 0.f);  // (b1, r0)
    float4 acc11 = make_float4(0.f, 0.f, 0.f, 0.f);  // (b1, r1)

    #pragma unroll 2
    for (int li = 0; li < 4; ++li) {
        // inputs for b0, b1 (l = li*32 + lg)
        const float4 x0  = *(const float4*)(X  + io);
        const float4 t0  = *(const float4*)(T  + io);
        const float4 m0  = *(const float4*)(M  + io);
        const float4 dt0 = *(const float4*)(DT + io);
        const float4 p0  = *(const float4*)(P  + io);
        const float4 x1  = *(const float4*)(X  + io + PL * PD);
        const float4 t1  = *(const float4*)(T  + io + PL * PD);
        const float4 m1  = *(const float4*)(M  + io + PL * PD);
        const float4 dt1 = *(const float4*)(DT + io + PL * PD);
        const float4 p1  = *(const float4*)(P  + io + PL * PD);

        // w_t for r0, r1 (20 contiguous floats each)
        float w0[20], w1[20];
        #pragma unroll
        for (int q = 0; q < 5; ++q) {
            *(float4*)(w0 + q * 4) = *(const float4*)(w_t + wo + q * 4);
            *(float4*)(w1 + q * 4) = *(const float4*)(w_t + wo + PL * PD * 5 + q * 4);
        }

        const float4 bt0 = *(const float4*)(b_t + vo);
        const float4 wv0 = *(const float4*)(w_v + vo);
        const float4 bt1 = *(const float4*)(b_t + vo + PL * PD);
        const float4 wv1 = *(const float4*)(w_v + vo + PL * PD);

        compute4(x0, t0, m0, dt0, p0, w0, bt0, wv0, ar0, refr0, acc00);
        compute4(x0, t0, m0, dt0, p0, w1, bt1, wv1, ar1, refr1, acc01);
        compute4(x1, t1, m1, dt1, p1, w0, bt0, wv0, ar0, refr0, acc10);
        compute4(x1, t1, m1, dt1, p1, w1, bt1, wv1, ar1, refr1, acc11);

        io += 32 * PD;        // l advances by 32
        wo += 32 * PD * 5;
        vo += 32 * PD;
    }

    // stage partials: o = bi*24 + ri*12 + dq
    part[lg][ 0 + dq] = acc00;
    part[lg][12 + dq] = acc01;
    part[lg][24 + dq] = acc10;
    part[lg][36 + dq] = acc11;
    __syncthreads();

    // stage-1 reduce: 192 threads, each sums 8 of the 32 L-groups
    if (tid < 192) {
        const int half = tid / 48;        // 0..3
        const int o = tid - half * 48;    // 0..47
        float4 s = part[half * 8][o];
        #pragma unroll
        for (int g = 1; g < 8; ++g) {
            const float4 q = part[half * 8 + g][o];
            s.x += q.x; s.y += q.y; s.z += q.z; s.w += q.w;
        }
        part2[half][o] = s;
    }
    __syncthreads();

    // stage-2: combine 4 partials + bias + relu + store
    if (tid < 48) {
        const int o = tid;
        const int bi = o / 24;             // 0..1
        const int ri = (o - bi * 24) / 12; // 0..1
        const int dqo = o - bi * 24 - ri * 12;
        float4 s = part2[0][o];
        #pragma unroll
        for (int g = 1; g < 4; ++g) {
            const float4 q = part2[g][o];
            s.x += q.x; s.y += q.y; s.z += q.z; s.w += q.w;
        }
        const int r = r0 + ri;
        const int b = b0 + bi;
        const float4 bv4 = *(const float4*)(b_v + r * PD + dqo * 4);
        s.x = fmaxf(s.x + 128.0f * bv4.x, 0.0f);   // b_v broadcast over L
        s.y = fmaxf(s.y + 128.0f * bv4.y, 0.0f);
        s.z = fmaxf(s.z + 128.0f * bv4.z, 0.0f);
        s.w = fmaxf(s.w + 128.0f * bv4.w, 0.0f);
        *(float4*)(out + b * (PR * PD) + r * PD + dqo * 4) = s;
    }
}

extern "C" void kernel_launch(void* const* d_in, const int* in_sizes, int n_in,
                              void* d_out, int out_size, void* d_ws, size_t ws_size,
                              hipStream_t stream) {
    // setup_inputs() order: X, T, M, DT, P, alpha, w_t, b_t, w_v, b_v (all f32)
    const float* X     = (const float*)d_in[0];
    const float* T     = (const float*)d_in[1];
    const float* M     = (const float*)d_in[2];
    const float* DT    = (const float*)d_in[3];
    const float* P     = (const float*)d_in[4];
    const float* alpha = (const float*)d_in[5];
    const float* w_t   = (const float*)d_in[6];
    const float* b_t   = (const float*)d_in[7];
    const float* w_v   = (const float*)d_in[8];
    const float* b_v   = (const float*)d_in[9];
    float* out = (float*)d_out;

    alnn_kernel<<<512, 384, 0, stream>>>(X, T, M, DT, P, alpha, w_t, b_t, w_v, b_v, out);
}

// Round 6
// 95.039 us; speedup vs baseline: 1.0652x; 1.0652x over previous
//
#include <hip/hip_runtime.h>
#include <hip/hip_bf16.h>

// Problem constants (from reference): B=32, L=128, D=48, R=64
#define PB 32
#define PL 128
#define PD 48
#define PR 64

// Register-tiled 4x2 (4 b's x 2 r's per block), grid = 8*32 = 256 blocks,
// 384 threads (6 waves, 1 block/CU). tid -> lg = tid/12 (L-group 0..31),
// dq = tid%12 (d-quad). Per l-step a thread loads 20 input float4s
// (5 tensors x 4 b), 10 w_t float4s (5 x 2 r) and 4 b_t/w_v float4s,
// computing 4x2x4 = 32 h-elements: 4.25 floats/element vs 6 in rounds 4-5
// (L2 demand 295 -> 209 MB). R5 showed occupancy is NOT the limiter
// (6 -> 12 waves/CU was a zero delta), so 6 waves/CU is enough.
__device__ __forceinline__ void compute4(
    const float4 x4, const float4 t4, const float4 m4, const float4 dt4,
    const float4 p4, const float* __restrict__ w20, const float4 bt4,
    const float4 wv4, const float ar, const float refr, float4& acc)
{
    const float xs[4]  = {x4.x,  x4.y,  x4.z,  x4.w};
    const float ts[4]  = {t4.x,  t4.y,  t4.z,  t4.w};
    const float ms[4]  = {m4.x,  m4.y,  m4.z,  m4.w};
    const float dts[4] = {dt4.x, dt4.y, dt4.z, dt4.w};
    const float ps[4]  = {p4.x,  p4.y,  p4.z,  p4.w};
    const float bts[4] = {bt4.x, bt4.y, bt4.z, bt4.w};
    const float wvs[4] = {wv4.x, wv4.y, wv4.z, wv4.w};
    float a[4] = {acc.x, acc.y, acc.z, acc.w};
    #pragma unroll
    for (int j = 0; j < 4; ++j) {
        const float x = xs[j];
        const float dist = fabsf(ts[j] - refr);
        const float kern = __expf(-ar * dist);
        float inten = x * kern;
        inten = inten > 0.0f ? inten : 0.0f;
        float h = w20[j*5 + 0] * x
                + w20[j*5 + 1] * inten
                + w20[j*5 + 2] * ms[j]
                + w20[j*5 + 3] * dts[j]
                + w20[j*5 + 4] * ps[j]
                + 5.0f * bts[j];              // b_t broadcast over 5-axis
        h = h > 0.0f ? h : 0.0f;
        a[j] += wvs[j] * h;
    }
    acc = make_float4(a[0], a[1], a[2], a[3]);
}

__global__ __launch_bounds__(384) void alnn_kernel(
    const float* __restrict__ X,
    const float* __restrict__ T,
    const float* __restrict__ M,
    const float* __restrict__ DT,
    const float* __restrict__ P,
    const float* __restrict__ alpha,
    const float* __restrict__ w_t,
    const float* __restrict__ b_t,
    const float* __restrict__ w_v,
    const float* __restrict__ b_v,
    float* __restrict__ out)
{
    const int bid = blockIdx.x;
    const int rrb = bid & 31;       // r-tile index 0..31
    const int bbb = bid >> 5;       // b-tile index 0..7
    const int r0 = rrb * 2;
    const int b0 = bbb * 4;
    const int tid = threadIdx.x;
    const int lg = tid / 12;        // 0..31
    const int dq = tid - lg * 12;   // 0..11

    // partials: [lg][bi*24 + ri*12 + dq], rows padded 96 -> 97
    __shared__ float4 part[32][97];
    __shared__ float4 part2[4][97];

    const float ar0 = fmaxf(alpha[r0], 0.0f);
    const float ar1 = fmaxf(alpha[r0 + 1], 0.0f);
    const float refr0 = 48.0f * (float)r0 / 63.0f;        // linspace(0,48,64)
    const float refr1 = 48.0f * (float)(r0 + 1) / 63.0f;

    int io = b0 * (PL * PD) + lg * PD + dq * 4;            // X/T/M/DT/P, b0
    int wo = r0 * (PL * PD * 5) + lg * (PD * 5) + dq * 20; // w_t, r0
    int vo = r0 * (PL * PD) + lg * PD + dq * 4;            // b_t/w_v, r0

    float4 acc[4][2];
    #pragma unroll
    for (int bi = 0; bi < 4; ++bi)
        #pragma unroll
        for (int ri = 0; ri < 2; ++ri)
            acc[bi][ri] = make_float4(0.f, 0.f, 0.f, 0.f);

    #pragma unroll 1
    for (int li = 0; li < 4; ++li) {
        // inputs for b0..b0+3 (l = li*32 + lg)
        float4 x4[4], t4[4], m4[4], dt4[4], p4[4];
        #pragma unroll
        for (int bi = 0; bi < 4; ++bi) {
            const int o = io + bi * (PL * PD);
            x4[bi]  = *(const float4*)(X  + o);
            t4[bi]  = *(const float4*)(T  + o);
            m4[bi]  = *(const float4*)(M  + o);
            dt4[bi] = *(const float4*)(DT + o);
            p4[bi]  = *(const float4*)(P  + o);
        }

        // w_t for r0, r1 (20 contiguous floats each)
        float w0[20], w1[20];
        #pragma unroll
        for (int q = 0; q < 5; ++q) {
            *(float4*)(w0 + q * 4) = *(const float4*)(w_t + wo + q * 4);
            *(float4*)(w1 + q * 4) = *(const float4*)(w_t + wo + PL * PD * 5 + q * 4);
        }

        const float4 bt0 = *(const float4*)(b_t + vo);
        const float4 wv0 = *(const float4*)(w_v + vo);
        const float4 bt1 = *(const float4*)(b_t + vo + PL * PD);
        const float4 wv1 = *(const float4*)(w_v + vo + PL * PD);

        #pragma unroll
        for (int bi = 0; bi < 4; ++bi) {
            compute4(x4[bi], t4[bi], m4[bi], dt4[bi], p4[bi], w0, bt0, wv0,
                     ar0, refr0, acc[bi][0]);
            compute4(x4[bi], t4[bi], m4[bi], dt4[bi], p4[bi], w1, bt1, wv1,
                     ar1, refr1, acc[bi][1]);
        }

        io += 32 * PD;        // l advances by 32
        wo += 32 * PD * 5;
        vo += 32 * PD;
    }

    // stage partials: o = bi*24 + ri*12 + dq
    #pragma unroll
    for (int bi = 0; bi < 4; ++bi)
        #pragma unroll
        for (int ri = 0; ri < 2; ++ri)
            part[lg][bi * 24 + ri * 12 + dq] = acc[bi][ri];
    __syncthreads();

    // stage-1 reduce: 384 threads, each sums 8 of the 32 L-groups
    {
        const int q = tid / 96;         // 0..3
        const int o = tid - q * 96;     // 0..95
        float4 s = part[q * 8][o];
        #pragma unroll
        for (int g = 1; g < 8; ++g) {
            const float4 v = part[q * 8 + g][o];
            s.x += v.x; s.y += v.y; s.z += v.z; s.w += v.w;
        }
        part2[q][o] = s;
    }
    __syncthreads();

    // stage-2: combine 4 partials + bias + relu + store
    if (tid < 96) {
        const int o = tid;
        const int bi = o / 24;             // 0..3
        const int ri = (o - bi * 24) / 12; // 0..1
        const int dqo = o - bi * 24 - ri * 12;
        float4 s = part2[0][o];
        #pragma unroll
        for (int g = 1; g < 4; ++g) {
            const float4 v = part2[g][o];
            s.x += v.x; s.y += v.y; s.z += v.z; s.w += v.w;
        }
        const int r = r0 + ri;
        const int b = b0 + bi;
        const float4 bv4 = *(const float4*)(b_v + r * PD + dqo * 4);
        s.x = fmaxf(s.x + 128.0f * bv4.x, 0.0f);   // b_v broadcast over L
        s.y = fmaxf(s.y + 128.0f * bv4.y, 0.0f);
        s.z = fmaxf(s.z + 128.0f * bv4.z, 0.0f);
        s.w = fmaxf(s.w + 128.0f * bv4.w, 0.0f);
        *(float4*)(out + b * (PR * PD) + r * PD + dqo * 4) = s;
    }
}

extern "C" void kernel_launch(void* const* d_in, const int* in_sizes, int n_in,
                              void* d_out, int out_size, void* d_ws, size_t ws_size,
                              hipStream_t stream) {
    // setup_inputs() order: X, T, M, DT, P, alpha, w_t, b_t, w_v, b_v (all f32)
    const float* X     = (const float*)d_in[0];
    const float* T     = (const float*)d_in[1];
    const float* M     = (const float*)d_in[2];
    const float* DT    = (const float*)d_in[3];
    const float* P     = (const float*)d_in[4];
    const float* alpha = (const float*)d_in[5];
    const float* w_t   = (const float*)d_in[6];
    const float* b_t   = (const float*)d_in[7];
    const float* w_v   = (const float*)d_in[8];
    const float* b_v   = (const float*)d_in[9];
    float* out = (float*)d_out;

    alnn_kernel<<<256, 384, 0, stream>>>(X, T, M, DT, P, alpha, w_t, b_t, w_v, b_v, out);
}